// Round 3
// baseline (1753.618 us; speedup 1.0000x reference)
//
#include <hip/hip_runtime.h>
#include <math.h>

#define B_TOT 2048
#define SEQL  49
#define HEADS 12
#define HDIM  32
#define CDIM  384
#define C3    1152
#define RTAB  169
#define KSTEPS 12          // 384 / 32

typedef __attribute__((ext_vector_type(8))) short s16x8;     // 8 bf16 (4 VGPR)
typedef __attribute__((ext_vector_type(8))) unsigned short u16x8;
typedef __attribute__((ext_vector_type(4))) float f32x4;

__device__ __forceinline__ unsigned short f2bf(float f) {    // RNE f32->bf16
  unsigned u = __float_as_uint(f);
  u += 0x7fffu + ((u >> 16) & 1u);
  return (unsigned short)(u >> 16);
}
__device__ __forceinline__ float bf2f(unsigned short h) {
  return __uint_as_float((unsigned)h << 16);
}

// ---------------------------------------------------------------------------
// conv_split_a: fp32 A[rows,384] -> hi/lo bf16, fragment-linear tiles.
// Tile (bt,ks) = 128 rows x 32 k, base elem (bt*12+ks)*4096. Slab mg (16
// rows) of 512; lane l=(g<<4)|r0 owns 8 contig elems = A[mg*16+r0][8g..8g+7].
// Same slot map as conv_split_b -> HW K-slot permutation cancels in MFMA.
// ---------------------------------------------------------------------------
__global__ __launch_bounds__(256) void conv_split_a(
    const float* __restrict__ A, unsigned short* __restrict__ Ah,
    unsigned short* __restrict__ Al)
{
  const int bid = blockIdx.x;            // bt*12 + ks (chunk-local)
  const int t = threadIdx.x;
  const int bt = bid / KSTEPS, ks = bid % KSTEPS;
  const int row_loc = t >> 1, half = t & 1;

  const float* src = A + (size_t)(bt * 128 + row_loc) * CDIM + ks * 32 + half * 16;
  float f[16];
  const float4* s4 = (const float4*)src;
#pragma unroll
  for (int i = 0; i < 4; ++i) {
    float4 v = s4[i];
    f[4*i] = v.x; f[4*i+1] = v.y; f[4*i+2] = v.z; f[4*i+3] = v.w;
  }
  const int mg = row_loc >> 4, r0 = row_loc & 15;
  const size_t base = (size_t)bid * 4096 + mg * 512;
#pragma unroll
  for (int rr = 0; rr < 2; ++rr) {
    const int g = 2 * half + rr;
    u16x8 vh, vl;
#pragma unroll
    for (int j = 0; j < 8; ++j) {
      float fv = f[8*rr + j];
      unsigned short h = f2bf(fv);
      vh[j] = h;
      vl[j] = f2bf(fv - bf2f(h));
    }
    const size_t addr = base + (size_t)(((g << 4) | r0)) * 8;
    *(u16x8*)&Ah[addr] = vh;
    *(u16x8*)&Al[addr] = vl;
  }
}

// ---------------------------------------------------------------------------
// conv_split_b: fp32 W[K,N] -> hi/lo bf16 fragment-linear tiles.
// Tile (nt,ks); slab nfrag (16 cols) of 512; lane l=(g<<4)|c0 owns
// W[ks*32+8g+j][nt*128+nfrag*16+c0], j=0..7.
// ---------------------------------------------------------------------------
__global__ __launch_bounds__(256) void conv_split_b(
    const float* __restrict__ W, unsigned short* __restrict__ Bh,
    unsigned short* __restrict__ Bl, int N)
{
  const int bid = blockIdx.x;            // nt*12 + ks
  const int nt = bid / KSTEPS, ks = bid % KSTEPS;
  const int t = threadIdx.x;
  for (int e = t; e < 512; e += 256) {
    const int nfrag = e >> 6, l = e & 63, g = l >> 4, c0 = l & 15;
    const float* src = W + (size_t)(ks * 32 + g * 8) * N + nt * 128 + nfrag * 16 + c0;
    u16x8 vh, vl;
#pragma unroll
    for (int j = 0; j < 8; ++j) {
      float fv = src[(size_t)j * N];
      unsigned short h = f2bf(fv);
      vh[j] = h;
      vl[j] = f2bf(fv - bf2f(h));
    }
    const size_t addr = (size_t)bid * 4096 + nfrag * 512 + (size_t)l * 8;
    *(u16x8*)&Bh[addr] = vh;
    *(u16x8*)&Bl[addr] = vl;
  }
}

// ---------------------------------------------------------------------------
// gemm_mfma: C[rows,N] = A@B + bias, split-bf16 3-product MFMA.
// 128x128 tile, BK=32, 256 thr = 2x2 waves, wave = 64x64 (4x4 frags of
// 16x16x32). A/B pre-formatted fragment-linear: staging = pure memcpy
// (coalesced float4, linear conflict-free LDS), frag reads ds_read_b128.
// ---------------------------------------------------------------------------
__global__ __launch_bounds__(256) void gemm_mfma(
    const unsigned short* __restrict__ Ah, const unsigned short* __restrict__ Al,
    const unsigned short* __restrict__ Bh, const unsigned short* __restrict__ Bl,
    const float* __restrict__ bias, float* __restrict__ Cm, int N)
{
  __shared__ unsigned short sm[4 * 4096];   // Ah | Al | Bh | Bl, 8KB each
  const int ntiles = N >> 7;
  const int bt = blockIdx.x / ntiles, nt = blockIdx.x % ntiles;
  const int t = threadIdx.x, lane = t & 63, wave = t >> 6;
  const int wr = wave >> 1, wc = wave & 1;

  f32x4 acc[4][4];
#pragma unroll
  for (int m = 0; m < 4; ++m)
#pragma unroll
    for (int n = 0; n < 4; ++n) acc[m][n] = (f32x4){0.f, 0.f, 0.f, 0.f};

  for (int ks = 0; ks < KSTEPS; ++ks) {
    const float4* pah = (const float4*)Ah + (size_t)(bt * KSTEPS + ks) * 512;
    const float4* pal = (const float4*)Al + (size_t)(bt * KSTEPS + ks) * 512;
    const float4* pbh = (const float4*)Bh + (size_t)(nt * KSTEPS + ks) * 512;
    const float4* pbl = (const float4*)Bl + (size_t)(nt * KSTEPS + ks) * 512;
    float4 a0 = pah[t], a1 = pah[t + 256];
    float4 b0 = pal[t], b1 = pal[t + 256];
    float4 c0 = pbh[t], c1 = pbh[t + 256];
    float4 d0 = pbl[t], d1 = pbl[t + 256];
    float4* s = (float4*)sm;
    s[t] = a0;        s[t + 256] = a1;
    s[512 + t] = b0;  s[512 + t + 256] = b1;
    s[1024 + t] = c0; s[1024 + t + 256] = c1;
    s[1536 + t] = d0; s[1536 + t + 256] = d1;
    __syncthreads();

    s16x8 fah[4], fal[4], fbh[4], fbl[4];
#pragma unroll
    for (int m = 0; m < 4; ++m) {
      fah[m] = *(const s16x8*)&sm[(size_t)(4 * wr + m) * 512 + lane * 8];
      fal[m] = *(const s16x8*)&sm[4096 + (size_t)(4 * wr + m) * 512 + lane * 8];
    }
#pragma unroll
    for (int n = 0; n < 4; ++n) {
      fbh[n] = *(const s16x8*)&sm[8192 + (size_t)(4 * wc + n) * 512 + lane * 8];
      fbl[n] = *(const s16x8*)&sm[12288 + (size_t)(4 * wc + n) * 512 + lane * 8];
    }
#pragma unroll
    for (int m = 0; m < 4; ++m)
#pragma unroll
      for (int n = 0; n < 4; ++n) {
        acc[m][n] = __builtin_amdgcn_mfma_f32_16x16x32_bf16(fah[m], fbh[n], acc[m][n], 0, 0, 0);
        acc[m][n] = __builtin_amdgcn_mfma_f32_16x16x32_bf16(fah[m], fbl[n], acc[m][n], 0, 0, 0);
        acc[m][n] = __builtin_amdgcn_mfma_f32_16x16x32_bf16(fal[m], fbh[n], acc[m][n], 0, 0, 0);
      }
    __syncthreads();
  }

  // epilogue: D[row][col]: col = lane&15, row = 4*(lane>>4)+r  [m89-verified]
  const int r0 = lane & 15, g4 = lane >> 4;
#pragma unroll
  for (int n = 0; n < 4; ++n) {
    const int gcol = nt * 128 + wc * 64 + n * 16 + r0;
    const float bv = bias[gcol];
#pragma unroll
    for (int m = 0; m < 4; ++m) {
      const int growb = bt * 128 + wr * 64 + m * 16 + g4 * 4;
#pragma unroll
      for (int r = 0; r < 4; ++r)
        Cm[(size_t)(growb + r) * N + gcol] = acc[m][n][r] + bv;
    }
  }
}

// ---------------------------------------------------------------------------
// Fused window attention (fp32). One block per (b_local,h), 256 thr (4
// waves). lane = query row i; waves split key dim j. rpe einsums = gathers
// from 169-row per-head LDS tables. Output -> hi/lo bf16 fragment-linear
// tiles (chunk-local A-operand of the proj GEMM). Static LDS 65228 B.
// ---------------------------------------------------------------------------
__global__ __launch_bounds__(256, 2) void win_attn(
    const float* __restrict__ qkv, const float* __restrict__ rpe,
    const float* __restrict__ mask,
    unsigned short* __restrict__ yh, unsigned short* __restrict__ yl, int b0)
{
  __shared__ float smQ[SEQL * 33];
  __shared__ float smK[SEQL * HDIM];
  __shared__ float smV[SEQL * HDIM];
  __shared__ float smT[2 * RTAB * 33];    // [0,5577)=Tk then Tv; rest=Tq then red
  __shared__ float smM[4 * 50];
  __shared__ float smS[4 * 50];

  const int blk  = blockIdx.x;
  const int h    = blk % HEADS;
  const int b    = blk / HEADS;           // chunk-local window index
  const int tid  = threadIdx.x;
  const int lane = tid & 63;
  const int wave = tid >> 6;
  const float scale = 0.17677669529663687f;   // 32^-0.5

  const float* qb = qkv + (size_t)b * SEQL * C3 + h * HDIM;
  for (int idx = tid; idx < SEQL * 8; idx += 256) {
    const int i = idx >> 3, cc = (idx & 7) << 2;
    float4 q4 = *(const float4*)(qb + (size_t)i * C3 + cc);
    smQ[i * 33 + cc]     = q4.x * scale; smQ[i * 33 + cc + 1] = q4.y * scale;
    smQ[i * 33 + cc + 2] = q4.z * scale; smQ[i * 33 + cc + 3] = q4.w * scale;
    float4 k4 = *(const float4*)(qb + (size_t)i * C3 + CDIM + cc);
    *(float4*)&smK[i * 32 + cc] = k4;
    float4 v4 = *(const float4*)(qb + (size_t)i * C3 + 2 * CDIM + cc);
    *(float4*)&smV[i * 32 + cc] = v4;
  }
  for (int idx = tid; idx < RTAB * 16; idx += 256) {
    const int r = idx >> 4, cc = (idx & 15) << 2;
    float4 t4 = *(const float4*)(rpe + (size_t)r * C3 + h * 96 + cc);
    if (cc < 32) {        // q_rpe (scaled; pairs with raw k)
      smT[RTAB * 33 + r * 33 + cc]     = t4.x * scale;
      smT[RTAB * 33 + r * 33 + cc + 1] = t4.y * scale;
      smT[RTAB * 33 + r * 33 + cc + 2] = t4.z * scale;
      smT[RTAB * 33 + r * 33 + cc + 3] = t4.w * scale;
    } else {              // k_rpe (raw; pairs with scaled q)
      const int c2 = cc - 32;
      smT[r * 33 + c2]     = t4.x; smT[r * 33 + c2 + 1] = t4.y;
      smT[r * 33 + c2 + 2] = t4.z; smT[r * 33 + c2 + 3] = t4.w;
    }
  }
  __syncthreads();

  const int  i   = lane;
  const bool act = (lane < SEQL);
  const int  ih  = i / 7, iw = i % 7;

  float qreg[32];
  if (act) {
#pragma unroll
    for (int c = 0; c < 32; ++c) qreg[c] = smQ[i * 33 + c];
  }

  float areg[13];
  float pmax = -1e30f;
  const float* mrow = mask + (size_t)((b0 + b) & 63) * SEQL * SEQL + (size_t)i * SEQL;
#pragma unroll
  for (int t = 0; t < 13; ++t) {
    const int jj = wave + 4 * t;
    float a = -1e30f;
    if (act && jj < SEQL) {
      const int r = (ih - jj / 7 + 6) * 13 + (iw - jj % 7 + 6);
      const float* tk = smT + r * 33;
      const float* tq = smT + RTAB * 33 + r * 33;
      const float* kj = smK + jj * 32;
      float s0 = 0.f;
#pragma unroll
      for (int c = 0; c < 32; ++c)
        s0 += qreg[c] * (kj[c] + tk[c]) + kj[c] * tq[c];
      a = s0 + mrow[jj];
      pmax = fmaxf(pmax, a);
    }
    areg[t] = a;
  }

  if (act) smM[wave * 50 + i] = pmax;
  __syncthreads();
  float m = -1e30f;
  if (act) {
#pragma unroll
    for (int w = 0; w < 4; ++w) m = fmaxf(m, smM[w * 50 + i]);
  }
  float ps = 0.f;
#pragma unroll
  for (int t = 0; t < 13; ++t) {
    const int jj = wave + 4 * t;
    float e = (act && jj < SEQL) ? __expf(areg[t] - m) : 0.f;
    areg[t] = e;
    ps += e;
  }
  if (act) smS[wave * 50 + i] = ps;
  __syncthreads();
  float inv = 1.f;
  if (act) {
    float s = 0.f;
#pragma unroll
    for (int w = 0; w < 4; ++w) s += smS[w * 50 + i];
    inv = 1.f / s;
  }

  // overwrite Tk region with Tv (all Tk/Tq reads done before the barriers)
  for (int idx = tid; idx < RTAB * 8; idx += 256) {
    const int r = idx >> 3, cc = (idx & 7) << 2;
    float4 t4 = *(const float4*)(rpe + (size_t)r * C3 + h * 96 + 64 + cc);
    smT[r * 33 + cc]     = t4.x; smT[r * 33 + cc + 1] = t4.y;
    smT[r * 33 + cc + 2] = t4.z; smT[r * 33 + cc + 3] = t4.w;
  }
  __syncthreads();

  float acc[32];
#pragma unroll
  for (int c = 0; c < 32; ++c) acc[c] = 0.f;
#pragma unroll
  for (int t = 0; t < 13; ++t) {
    const int jj = wave + 4 * t;
    if (act && jj < SEQL) {
      const float p = areg[t];
      const int r = (ih - jj / 7 + 6) * 13 + (iw - jj % 7 + 6);
      const float* tv = smT + r * 33;
      const float* vj = smV + jj * 32;
#pragma unroll
      for (int c = 0; c < 32; ++c) acc[c] = fmaf(p, vj[c] + tv[c], acc[c]);
    }
  }

  float* red = smT + RTAB * 33;   // disjoint from Tv region
  if (wave > 0 && act) {
#pragma unroll
    for (int c = 0; c < 32; ++c) red[(wave - 1) * 1617 + i * 33 + c] = acc[c];
  }
  __syncthreads();
  if (wave == 0 && act) {
#pragma unroll
    for (int w = 0; w < 3; ++w)
#pragma unroll
      for (int c = 0; c < 32; ++c) acc[c] += red[w * 1617 + i * 33 + c];

    // emit hi/lo bf16 fragment-linear tiles (chunk-local rows; k-step = h)
    const int grow = b * SEQL + i;
    const int rt = grow >> 7, rr = grow & 127;
    const int mg = rr >> 4, r0q = rr & 15;
    const size_t tbase = (size_t)(rt * KSTEPS + h) * 4096 + mg * 512;
#pragma unroll
    for (int g = 0; g < 4; ++g) {
      u16x8 vh, vl;
#pragma unroll
      for (int j = 0; j < 8; ++j) {
        float f = acc[g * 8 + j] * inv;
        unsigned short hh = f2bf(f);
        vh[j] = hh;
        vl[j] = f2bf(f - bf2f(hh));
      }
      const size_t addr = tbase + (size_t)(((g << 4) | r0q)) * 8;
      *(u16x8*)&yh[addr] = vh;
      *(u16x8*)&yl[addr] = vl;
    }
  }
}

// ---------------------------------------------------------------------------
extern "C" void kernel_launch(void* const* d_in, const int* in_sizes, int n_in,
                              void* d_out, int out_size, void* d_ws, size_t ws_size,
                              hipStream_t stream)
{
  const float* x         = (const float*)d_in[0];  // [2048,49,384]
  const float* attn_mask = (const float*)d_in[1];  // [64,49,49]
  const float* qkv_w     = (const float*)d_in[2];  // [384,1152]
  const float* qkv_b     = (const float*)d_in[3];  // [1152]
  const float* rpe_tab   = (const float*)d_in[4];  // [169,1152]
  const float* proj_w    = (const float*)d_in[5];  // [384,384]
  const float* proj_b    = (const float*)d_in[6];  // [384]
  float* out = (float*)d_out;                      // [2048,49,384]

  const int M = B_TOT * SEQL;                      // 100352
  const size_t WQ = (size_t)CDIM * C3 * 2;         // 884736 B per qkv weight buf
  const size_t WP = (size_t)CDIM * CDIM * 2;       // 294912 B per proj weight buf

  // adaptive chunking: pick the fewest chunks whose workspace fits ws_size.
  // per chunk: frag hi/lo (rows*384*2 B each, x-frags reused for y-frags)
  // + fp32 qkv (rows*1152*4 B). b-chunks of 128 windows align 49-row windows
  // to 128-row M-tiles exactly.
  int nchunk = 16;
  const int cands[5] = {1, 2, 4, 8, 16};
  for (int ci = 0; ci < 5; ++ci) {
    const int n = cands[ci];
    const size_t rows = (size_t)M / n;
    const size_t need = 2 * WQ + 2 * WP + 2 * rows * CDIM * 2 + rows * C3 * 4;
    if (need <= ws_size) { nchunk = n; break; }
  }
  const int b_per  = B_TOT / nchunk;
  const int rows_c = b_per * SEQL;
  const int tiles  = rows_c / 128;

  char* p = (char*)d_ws;
  unsigned short* wh_qkv = (unsigned short*)p;            p += WQ;
  unsigned short* wl_qkv = (unsigned short*)p;            p += WQ;
  unsigned short* wh_pro = (unsigned short*)p;            p += WP;
  unsigned short* wl_pro = (unsigned short*)p;            p += WP;
  unsigned short* fh     = (unsigned short*)p;            p += (size_t)rows_c * CDIM * 2;
  unsigned short* fl     = (unsigned short*)p;            p += (size_t)rows_c * CDIM * 2;
  float*          qkv_c  = (float*)p;

  conv_split_b<<<dim3(9 * KSTEPS), 256, 0, stream>>>(qkv_w, wh_qkv, wl_qkv, C3);
  conv_split_b<<<dim3(3 * KSTEPS), 256, 0, stream>>>(proj_w, wh_pro, wl_pro, CDIM);

  for (int c = 0; c < nchunk; ++c) {
    const size_t row0 = (size_t)c * rows_c;
    conv_split_a<<<dim3(tiles * KSTEPS), 256, 0, stream>>>(
        x + row0 * CDIM, fh, fl);
    gemm_mfma<<<dim3(tiles * 9), 256, 0, stream>>>(
        fh, fl, wh_qkv, wl_qkv, qkv_b, qkv_c, C3);
    win_attn<<<dim3(b_per * HEADS), 256, 0, stream>>>(
        qkv_c, rpe_tab, attn_mask, fh, fl, c * b_per);
    gemm_mfma<<<dim3(tiles * 3), 256, 0, stream>>>(
        fh, fl, wh_pro, wl_pro, proj_b, out + row0 * CDIM, CDIM);
  }
}